// Round 15
// baseline (223.834 us; speedup 1.0000x reference)
//
#include <hip/hip_runtime.h>
#include <hip/hip_bf16.h>
#include <math.h>

#define Hd 128
#define Tt 256
#define Bb 1024
#define CL 32           // time-chunk length
#define NCK (Tt / CL)   // 8 chunks

typedef __attribute__((ext_vector_type(8))) short short8;
typedef __attribute__((ext_vector_type(4))) float f32x4;

__device__ __forceinline__ short f2bf(float f) {
    unsigned u = __float_as_uint(f);
    u += 0x7fffu + ((u >> 16) & 1u);   // RNE
    return (short)(u >> 16);
}
__device__ __forceinline__ float bflo(unsigned u) { return __uint_as_float(u << 16); }
__device__ __forceinline__ float bfhi(unsigned u) { return __uint_as_float(u & 0xffff0000u); }

// Weights -> bf16 MFMA B-frag layout [nt][kf][lane][8].  (verbatim)
__global__ void prep_weights(const float* __restrict__ Wih,
                             const float* __restrict__ Whh,
                             const float* __restrict__ fcW,
                             short* __restrict__ oIh, short* __restrict__ oHh,
                             short* __restrict__ oFc) {
    int t = blockIdx.x * 256 + threadIdx.x;
    if (t >= 14336) return;
    const float* src;
    short* dst;
    if (t < 6144)       { src = Wih; dst = oIh + t * 8; }
    else if (t < 12288) { t -= 6144;  src = Whh; dst = oHh + t * 8; }
    else                { t -= 12288; src = fcW; dst = oFc + t * 8; }
    int lane = t & 63, kf = (t >> 6) & 3, nt = t >> 8;
    const float* s = src + (nt * 16 + (lane & 15)) * 128 + kf * 32 + 8 * (lane >> 4);
#pragma unroll
    for (int j = 0; j < 8; j++) dst[j] = f2bf(s[j]);
}

// K2: xi = x@W_ih^T (+bih, +bhh for r/z cols) in C-frag order. (verbatim R14:
// 8 frames/block, 2048 blocks). Records remain 16-batch groups (64 bg).
__global__ __launch_bounds__(512)
void xi_gemm(const float* __restrict__ x, const float* __restrict__ bih,
             const float* __restrict__ bhh, const short* __restrict__ wIh,
             short* __restrict__ xi_l) {
    __shared__ short xs[128 * 136];
    const int tid = threadIdx.x, wv = tid >> 6, ln = tid & 63;
    const int q = ln & 15, lg = ln >> 4;
    const int bg = blockIdx.x;
    const int sl0 = blockIdx.y * 8;
    {
        const int row = tid >> 2, kq = tid & 3;
        const int b = row & 15, dt = row >> 4;
        const float* xp = x + (((size_t)(bg * 16 + b)) * Tt + (sl0 + dt)) * Hd + kq * 32;
        short* dp = &xs[row * 136 + kq * 32];
#pragma unroll
        for (int h = 0; h < 2; h++) {
            f32x4 u0 = *(const f32x4*)&xp[16 * h];
            f32x4 u1 = *(const f32x4*)&xp[16 * h + 4];
            f32x4 u2 = *(const f32x4*)&xp[16 * h + 8];
            f32x4 u3 = *(const f32x4*)&xp[16 * h + 12];
            short8 s0, s1;
#pragma unroll
            for (int i = 0; i < 4; i++) { s0[i] = f2bf(u0[i]); s0[i+4] = f2bf(u1[i]);
                                          s1[i] = f2bf(u2[i]); s1[i+4] = f2bf(u3[i]); }
            *(short8*)(dp + 16 * h) = s0;
            *(short8*)(dp + 16 * h + 8) = s1;
        }
    }
    __syncthreads();
    short8 wb[3][4];
#pragma unroll
    for (int i = 0; i < 3; i++)
#pragma unroll
        for (int kf = 0; kf < 4; kf++)
            wb[i][kf] = *(const short8*)&wIh[(((wv + 8 * i) * 4 + kf) * 64 + ln) * 8];
    float biasv[3];
#pragma unroll
    for (int i = 0; i < 3; i++) {
        int c = (wv + 8 * i) * 16 + q;
        biasv[i] = bih[c] + (c < 256 ? bhh[c] : 0.f);
    }
#pragma unroll 2
    for (int mt = 0; mt < 8; mt++) {
        short8 af[4];
#pragma unroll
        for (int kf = 0; kf < 4; kf++)
            af[kf] = *(const short8*)&xs[(mt * 16 + q) * 136 + kf * 32 + 8 * lg];
        f32x4 c0 = {0,0,0,0}, c1 = {0,0,0,0}, c2 = {0,0,0,0};
#pragma unroll
        for (int kf = 0; kf < 4; kf++) {
            c0 = __builtin_amdgcn_mfma_f32_16x16x32_bf16(af[kf], wb[0][kf], c0, 0, 0, 0);
            c1 = __builtin_amdgcn_mfma_f32_16x16x32_bf16(af[kf], wb[1][kf], c1, 0, 0, 0);
            c2 = __builtin_amdgcn_mfma_f32_16x16x32_bf16(af[kf], wb[2][kf], c2, 0, 0, 0);
        }
#pragma unroll
        for (int i = 0; i < 3; i++) {
            f32x4 cc = (i == 0) ? c0 : (i == 1) ? c1 : c2;
            unsigned d0 = (unsigned)(unsigned short)f2bf(cc[0] + biasv[i]) |
                          ((unsigned)(unsigned short)f2bf(cc[1] + biasv[i]) << 16);
            unsigned d1 = (unsigned)(unsigned short)f2bf(cc[2] + biasv[i]) |
                          ((unsigned)(unsigned short)f2bf(cc[3] + biasv[i]) << 16);
            uint2 dd = {d0, d1};
            ((uint2*)xi_l)[(((size_t)bg * Tt + (sl0 + mt)) * 24 + (wv + 8 * i)) * 64 + ln] = dd;
        }
    }
}

// K3: R15 = R12's proven 4-wave structure, but 8 BATCHES per block ->
// grid 128x8 = 1024 blocks (R12: 512 was a GRID ceiling at 2 blocks/CU,
// VALUBusy 52% = stalled half the time; ~160 combined regs allow 3 blocks/CU).
// hT rows 0-7 live, 8-15 zero; gates/stores guarded to lg<2; xi records stay
// 16-batch: half-record selected via lane offset (2h+(lg&1))*16+q.
__global__ __launch_bounds__(256)
void gru_chunk(const short* __restrict__ xi_l, const int* __restrict__ done,
               const float* __restrict__ h0,
               const float* __restrict__ bhh, const float* __restrict__ fcb,
               const short* __restrict__ wHh, const short* __restrict__ wFc,
               float* __restrict__ out, float* __restrict__ hlast) {
    __shared__ short hT[2][16 * 136];
    __shared__ int doneL[Tt * 8];
    __shared__ int rbL[8];
    const int tid = threadIdx.x, j = tid >> 6, ln = tid & 63;
    const int q = ln & 15, lg = ln >> 4;
    const int gb = blockIdx.x, ck = blockIdx.y;
    const int g16 = gb >> 1, h = gb & 1;      // 16-batch xi group, half
    const int t_c = ck * CL, t_end = t_c + CL;

    {   // stage done[b][0..t_end) -> doneL[t][b], b in 0..7
        const int b = tid >> 5, i = tid & 31;
        const int* dp = done + (size_t)(gb * 8 + b) * Tt;
        for (int t = i; t < t_end; t += 32) doneL[t * 8 + b] = dp[t];
    }
    __syncthreads();
    if (tid < 8) {   // last reset before t_c
        int r = 0;
        for (int t = t_c - 1; t >= 0; --t)
            if (doneL[t * 8 + tid]) { r = t + 1; break; }
        rbL[tid] = r;
    }
    __syncthreads();
    int rmin = rbL[0];
#pragma unroll
    for (int b = 1; b < 8; b++) rmin = min(rmin, rbL[b]);

    short8 whh[6][4], wfc[2][4];
#pragma unroll
    for (int i = 0; i < 6; i++)
#pragma unroll
        for (int kf = 0; kf < 4; kf++)
            whh[i][kf] = *(const short8*)&wHh[(((j + 4 * i) * 4 + kf) * 64 + ln) * 8];
#pragma unroll
    for (int cs = 0; cs < 2; cs++)
#pragma unroll
        for (int kf = 0; kf < 4; kf++)
            wfc[cs][kf] = *(const short8*)&wFc[(((j + 4 * cs) * 4 + kf) * 64 + ln) * 8];
    float cbn[2], cbf[2];
#pragma unroll
    for (int cs = 0; cs < 2; cs++) {
        int c = 16 * j + 64 * cs + q;
        cbn[cs] = bhh[256 + c];
        cbf[cs] = fcb[c];
    }

    const bool act = (lg < 2);                 // thread owns batch bb = 4lg+r < 8
    float h_reg[2][4];
#pragma unroll
    for (int cs = 0; cs < 2; cs++)
#pragma unroll
        for (int r = 0; r < 4; r++) {
            int bb = (4 * lg + r) & 7, c = 16 * j + 64 * cs + q;
            h_reg[cs][r] = (act && rbL[bb] == 0)
                               ? h0[(size_t)(gb * 8 + bb) * Hd + c] : 0.f;
        }
    {   // zero both hT slots; fill slot rmin&1 rows<8 where rbL==0
        int row = tid >> 4, c0 = (tid & 15) * 8;
        short8 z8 = {0,0,0,0,0,0,0,0};
        short8 s0 = z8;
        if (row < 8 && rbL[row] == 0) {
            const float* hp = &h0[(size_t)(gb * 8 + row) * Hd + c0];
            f32x4 u0 = *(const f32x4*)&hp[0], u1 = *(const f32x4*)&hp[4];
#pragma unroll
            for (int i = 0; i < 4; i++) { s0[i] = f2bf(u0[i]); s0[i+4] = f2bf(u1[i]); }
        }
        *(short8*)&hT[(rmin & 1) ^ 1][row * 136 + c0] = z8;
        *(short8*)&hT[rmin & 1][row * 136 + c0] = s0;
    }
    __syncthreads();

    // xi: 16-batch records; this block's half -> lane pos (2h+(lg&1))*16+q
    const int lnx = (2 * h + (lg & 1)) * 16 + q;
    const uint2* xp = (const uint2*)xi_l + ((size_t)g16 * Tt + rmin) * 1536 + j * 64 + lnx;
    uint2 cur[6];
#pragma unroll
    for (int i = 0; i < 6; i++) cur[i] = xp[i * 256];
    xp += 1536;

#pragma unroll 1
    for (int t = rmin; t < t_end; ++t) {
        const short* hTp = &hT[t & 1][0];
        short* hTn = &hT[(t + 1) & 1][0];
        short8 haf[4];
#pragma unroll
        for (int kf = 0; kf < 4; kf++)
            haf[kf] = *(const short8*)&hTp[q * 136 + kf * 32 + 8 * lg];

        f32x4 acc[6];
#pragma unroll
        for (int i = 0; i < 4; i++) {
            f32x4 a = {bflo(cur[i].x), bfhi(cur[i].x), bflo(cur[i].y), bfhi(cur[i].y)};
            acc[i] = a;
        }
        { f32x4 a = {cbn[0], cbn[0], cbn[0], cbn[0]}; acc[4] = a; }
        { f32x4 a = {cbn[1], cbn[1], cbn[1], cbn[1]}; acc[5] = a; }
        uint2 xn8[2] = {cur[4], cur[5]};
        if (t + 1 < t_end) {
#pragma unroll
            for (int i = 0; i < 6; i++) cur[i] = xp[i * 256];
        }
        xp += 1536;

        if (t > t_c) {   // FC+ELU+stores for frame t-1 (un-reset haf)
            f32x4 fca[2];
            { f32x4 a = {cbf[0], cbf[0], cbf[0], cbf[0]}; fca[0] = a; }
            { f32x4 a = {cbf[1], cbf[1], cbf[1], cbf[1]}; fca[1] = a; }
#pragma unroll
            for (int kf = 0; kf < 4; kf++)
#pragma unroll
                for (int cs = 0; cs < 2; cs++)
                    fca[cs] = __builtin_amdgcn_mfma_f32_16x16x32_bf16(haf[kf], wfc[cs][kf], fca[cs], 0, 0, 0);
            if (act) {
#pragma unroll
                for (int cs = 0; cs < 2; cs++)
#pragma unroll
                    for (int r = 0; r < 4; r++) {
                        int bb = 4 * lg + r, c = 16 * j + 64 * cs + q;
                        float v = fca[cs][r];
                        float e = __expf(v) - 1.f;
                        v = v > 0.f ? v : e;
                        out[(((size_t)(gb * 8 + bb)) * Tt + (t - 1)) * Hd + c] = v;
                    }
            }
        }

        if (t > 0) {   // reset haf in place (rows>=8 are zero; index clamped)
            int dn = doneL[(t - 1) * 8 + (q & 7)];
            short8 z8 = {0,0,0,0,0,0,0,0};
#pragma unroll
            for (int kf = 0; kf < 4; kf++) haf[kf] = dn ? z8 : haf[kf];
        }
        __builtin_amdgcn_s_setprio(1);   // favor the h-critical region
#pragma unroll
        for (int kf = 0; kf < 4; kf++)
#pragma unroll
            for (int i = 0; i < 6; i++)
                acc[i] = __builtin_amdgcn_mfma_f32_16x16x32_bf16(haf[kf], whh[i][kf], acc[i], 0, 0, 0);

        float rstf[4] = {1.f, 1.f, 1.f, 1.f};
        if (t > 0) {
            int4 dd = *(const int4*)&doneL[(t - 1) * 8 + ((4 * lg) & 7)];
            rstf[0] = dd.x ? 0.f : 1.f; rstf[1] = dd.y ? 0.f : 1.f;
            rstf[2] = dd.z ? 0.f : 1.f; rstf[3] = dd.w ? 0.f : 1.f;
        }
#pragma unroll
        for (int cs = 0; cs < 2; cs++) {
#pragma unroll
            for (int r = 0; r < 4; r++) {
                float rg = __builtin_amdgcn_rcpf(1.f + __expf(-acc[cs][r]));
                float zg = __builtin_amdgcn_rcpf(1.f + __expf(-acc[2 + cs][r]));
                float xn = (r == 0) ? bflo(xn8[cs].x) : (r == 1) ? bfhi(xn8[cs].x)
                         : (r == 2) ? bflo(xn8[cs].y) : bfhi(xn8[cs].y);
                float aa = fmaf(rg, acc[4 + cs][r], xn);
                float ng = 1.f - 2.f * __builtin_amdgcn_rcpf(__expf(2.f * aa) + 1.f);
                float hp = h_reg[cs][r] * rstf[r];
                float hn = (1.f - zg) * ng + zg * hp;
                h_reg[cs][r] = hn;                       // un-reset
                if (act)
                    hTn[(4 * lg + r) * 136 + 16 * j + 64 * cs + q] = f2bf(hn);
            }
        }
        __builtin_amdgcn_s_setprio(0);
        // raw barrier: lgkmcnt(0) only, semantic intrinsic
        __builtin_amdgcn_sched_barrier(0);
        __builtin_amdgcn_s_waitcnt(0xC07F);
        __builtin_amdgcn_s_barrier();
        __builtin_amdgcn_sched_barrier(0);
    }
    {   // epilogue FC for frame t_end-1 (slot t_end&1 holds h_{t_end-1})
        const short* hTp = &hT[t_end & 1][0];
        short8 haf[4];
#pragma unroll
        for (int kf = 0; kf < 4; kf++)
            haf[kf] = *(const short8*)&hTp[q * 136 + kf * 32 + 8 * lg];
        f32x4 fca[2];
        { f32x4 a = {cbf[0], cbf[0], cbf[0], cbf[0]}; fca[0] = a; }
        { f32x4 a = {cbf[1], cbf[1], cbf[1], cbf[1]}; fca[1] = a; }
#pragma unroll
        for (int kf = 0; kf < 4; kf++)
#pragma unroll
            for (int cs = 0; cs < 2; cs++)
                fca[cs] = __builtin_amdgcn_mfma_f32_16x16x32_bf16(haf[kf], wfc[cs][kf], fca[cs], 0, 0, 0);
        if (act) {
#pragma unroll
            for (int cs = 0; cs < 2; cs++)
#pragma unroll
                for (int r = 0; r < 4; r++) {
                    int bb = 4 * lg + r, c = 16 * j + 64 * cs + q;
                    float v = fca[cs][r];
                    float e = __expf(v) - 1.f;
                    v = v > 0.f ? v : e;
                    out[(((size_t)(gb * 8 + bb)) * Tt + (t_end - 1)) * Hd + c] = v;
                }
        }
    }
    if (ck == NCK - 1 && act) {   // h after step 255, un-reset
#pragma unroll
        for (int cs = 0; cs < 2; cs++)
#pragma unroll
            for (int r = 0; r < 4; r++) {
                int bb = 4 * lg + r, c = 16 * j + 64 * cs + q;
                hlast[(size_t)(gb * 8 + bb) * Hd + c] = h_reg[cs][r];
            }
    }
}

extern "C" void kernel_launch(void* const* d_in, const int* in_sizes, int n_in,
                              void* d_out, int out_size, void* d_ws, size_t ws_size,
                              hipStream_t stream) {
    const float* x   = (const float*)d_in[0];
    const float* h0  = (const float*)d_in[1];
    const int*   dn  = (const int*)d_in[2];
    const float* Wih = (const float*)d_in[3];
    const float* Whh = (const float*)d_in[4];
    const float* bih = (const float*)d_in[5];
    const float* bhh = (const float*)d_in[6];
    const float* fcW = (const float*)d_in[7];
    const float* fcb = (const float*)d_in[8];

    short* wIh = (short*)d_ws;                 // 96 KB
    short* wHh = wIh + 49152;                  // 96 KB
    short* wFc = wHh + 49152;                  // 32 KB
    short* xi_l = wFc + 16384;                 // full-T xi: 201 MB
    float* out = (float*)d_out;
    float* hlast = out + (size_t)Bb * Tt * Hd;

    prep_weights<<<56, 256, 0, stream>>>(Wih, Whh, fcW, wIh, wHh, wFc);
    xi_gemm<<<dim3(64, Tt / 8), 512, 0, stream>>>(x, bih, bhh, wIh, xi_l);
    gru_chunk<<<dim3(128, NCK), 256, 0, stream>>>(xi_l, dn, h0, bhh, fcb,
                                                  wHh, wFc, out, hlast);
}

// Round 16
// 211.025 us; speedup vs baseline: 1.0607x; 1.0607x over previous
//
#include <hip/hip_runtime.h>
#include <hip/hip_bf16.h>
#include <math.h>

#define Hd 128
#define Tt 256
#define Bb 1024
#define CL 16           // chunk length; blocks own a PAIR of chunks (dual-rec)
#define NPAIR 8         // 16 chunks / 2

typedef __attribute__((ext_vector_type(8))) short short8;
typedef __attribute__((ext_vector_type(4))) float f32x4;

__device__ __forceinline__ short f2bf(float f) {
    unsigned u = __float_as_uint(f);
    u += 0x7fffu + ((u >> 16) & 1u);   // RNE
    return (short)(u >> 16);
}
__device__ __forceinline__ float bflo(unsigned u) { return __uint_as_float(u << 16); }
__device__ __forceinline__ float bfhi(unsigned u) { return __uint_as_float(u & 0xffff0000u); }

// Weights -> bf16 MFMA B-frag layout [nt][kf][lane][8].  (verbatim)
__global__ void prep_weights(const float* __restrict__ Wih,
                             const float* __restrict__ Whh,
                             const float* __restrict__ fcW,
                             short* __restrict__ oIh, short* __restrict__ oHh,
                             short* __restrict__ oFc) {
    int t = blockIdx.x * 256 + threadIdx.x;
    if (t >= 14336) return;
    const float* src;
    short* dst;
    if (t < 6144)       { src = Wih; dst = oIh + t * 8; }
    else if (t < 12288) { t -= 6144;  src = Whh; dst = oHh + t * 8; }
    else                { t -= 12288; src = fcW; dst = oFc + t * 8; }
    int lane = t & 63, kf = (t >> 6) & 3, nt = t >> 8;
    const float* s = src + (nt * 16 + (lane & 15)) * 128 + kf * 32 + 8 * (lane >> 4);
#pragma unroll
    for (int j = 0; j < 8; j++) dst[j] = f2bf(s[j]);
}

// K2: xi = x@W_ih^T (+bih, +bhh for r/z cols) in C-frag order. (verbatim R14)
__global__ __launch_bounds__(512)
void xi_gemm(const float* __restrict__ x, const float* __restrict__ bih,
             const float* __restrict__ bhh, const short* __restrict__ wIh,
             short* __restrict__ xi_l) {
    __shared__ short xs[128 * 136];
    const int tid = threadIdx.x, wv = tid >> 6, ln = tid & 63;
    const int q = ln & 15, lg = ln >> 4;
    const int bg = blockIdx.x;
    const int sl0 = blockIdx.y * 8;
    {
        const int row = tid >> 2, kq = tid & 3;
        const int b = row & 15, dt = row >> 4;
        const float* xp = x + (((size_t)(bg * 16 + b)) * Tt + (sl0 + dt)) * Hd + kq * 32;
        short* dp = &xs[row * 136 + kq * 32];
#pragma unroll
        for (int h = 0; h < 2; h++) {
            f32x4 u0 = *(const f32x4*)&xp[16 * h];
            f32x4 u1 = *(const f32x4*)&xp[16 * h + 4];
            f32x4 u2 = *(const f32x4*)&xp[16 * h + 8];
            f32x4 u3 = *(const f32x4*)&xp[16 * h + 12];
            short8 s0, s1;
#pragma unroll
            for (int i = 0; i < 4; i++) { s0[i] = f2bf(u0[i]); s0[i+4] = f2bf(u1[i]);
                                          s1[i] = f2bf(u2[i]); s1[i+4] = f2bf(u3[i]); }
            *(short8*)(dp + 16 * h) = s0;
            *(short8*)(dp + 16 * h + 8) = s1;
        }
    }
    __syncthreads();
    short8 wb[3][4];
#pragma unroll
    for (int i = 0; i < 3; i++)
#pragma unroll
        for (int kf = 0; kf < 4; kf++)
            wb[i][kf] = *(const short8*)&wIh[(((wv + 8 * i) * 4 + kf) * 64 + ln) * 8];
    float biasv[3];
#pragma unroll
    for (int i = 0; i < 3; i++) {
        int c = (wv + 8 * i) * 16 + q;
        biasv[i] = bih[c] + (c < 256 ? bhh[c] : 0.f);
    }
#pragma unroll 2
    for (int mt = 0; mt < 8; mt++) {
        short8 af[4];
#pragma unroll
        for (int kf = 0; kf < 4; kf++)
            af[kf] = *(const short8*)&xs[(mt * 16 + q) * 136 + kf * 32 + 8 * lg];
        f32x4 c0 = {0,0,0,0}, c1 = {0,0,0,0}, c2 = {0,0,0,0};
#pragma unroll
        for (int kf = 0; kf < 4; kf++) {
            c0 = __builtin_amdgcn_mfma_f32_16x16x32_bf16(af[kf], wb[0][kf], c0, 0, 0, 0);
            c1 = __builtin_amdgcn_mfma_f32_16x16x32_bf16(af[kf], wb[1][kf], c1, 0, 0, 0);
            c2 = __builtin_amdgcn_mfma_f32_16x16x32_bf16(af[kf], wb[2][kf], c2, 0, 0, 0);
        }
#pragma unroll
        for (int i = 0; i < 3; i++) {
            f32x4 cc = (i == 0) ? c0 : (i == 1) ? c1 : c2;
            unsigned d0 = (unsigned)(unsigned short)f2bf(cc[0] + biasv[i]) |
                          ((unsigned)(unsigned short)f2bf(cc[1] + biasv[i]) << 16);
            unsigned d1 = (unsigned)(unsigned short)f2bf(cc[2] + biasv[i]) |
                          ((unsigned)(unsigned short)f2bf(cc[3] + biasv[i]) << 16);
            uint2 dd = {d0, d1};
            ((uint2*)xi_l)[(((size_t)bg * Tt + (sl0 + mt)) * 24 + (wv + 8 * i)) * 64 + ln] = dd;
        }
    }
}

// One recurrence step (R12 body, parameterized). __forceinline__ + static
// indices -> all state stays in registers after inlining.
__device__ __forceinline__ void gru_step(
    int t, int t_c, bool pf,
    const short* hTp, short* hTn,
    uint2 (&cur)[6], const uint2* xp,
    float (&h_reg)[2][4],
    const int* doneL,
    const short8 (&whh)[6][4], const short8 (&wfc)[2][4],
    const float (&cbn)[2], const float (&cbf)[2],
    float* __restrict__ out, int bg, int j, int q, int lg) {
    short8 haf[4];
#pragma unroll
    for (int kf = 0; kf < 4; kf++)
        haf[kf] = *(const short8*)&hTp[q * 136 + kf * 32 + 8 * lg];

    f32x4 acc[6];
#pragma unroll
    for (int i = 0; i < 4; i++) {
        f32x4 a = {bflo(cur[i].x), bfhi(cur[i].x), bflo(cur[i].y), bfhi(cur[i].y)};
        acc[i] = a;
    }
    { f32x4 a = {cbn[0], cbn[0], cbn[0], cbn[0]}; acc[4] = a; }
    { f32x4 a = {cbn[1], cbn[1], cbn[1], cbn[1]}; acc[5] = a; }
    uint2 xn8[2] = {cur[4], cur[5]};
    if (pf) {   // issue loads for t+1 (older than this step's stores)
#pragma unroll
        for (int i = 0; i < 6; i++) cur[i] = xp[i * 256];
    }

    if (t > t_c) {   // FC+ELU+stores for frame t-1 (un-reset haf)
        f32x4 fca[2];
        { f32x4 a = {cbf[0], cbf[0], cbf[0], cbf[0]}; fca[0] = a; }
        { f32x4 a = {cbf[1], cbf[1], cbf[1], cbf[1]}; fca[1] = a; }
#pragma unroll
        for (int kf = 0; kf < 4; kf++)
#pragma unroll
            for (int cs = 0; cs < 2; cs++)
                fca[cs] = __builtin_amdgcn_mfma_f32_16x16x32_bf16(haf[kf], wfc[cs][kf], fca[cs], 0, 0, 0);
#pragma unroll
        for (int cs = 0; cs < 2; cs++)
#pragma unroll
            for (int r = 0; r < 4; r++) {
                int bb = 4 * lg + r, c = 16 * j + 64 * cs + q;
                float v = fca[cs][r];
                float e = __expf(v) - 1.f;
                v = v > 0.f ? v : e;
                out[(((size_t)(bg * 16 + bb)) * Tt + (t - 1)) * Hd + c] = v;
            }
    }

    if (t > 0) {   // reset haf in place (FC above used un-reset value)
        int dn = doneL[(t - 1) * 16 + q];
        short8 z8 = {0,0,0,0,0,0,0,0};
#pragma unroll
        for (int kf = 0; kf < 4; kf++) haf[kf] = dn ? z8 : haf[kf];
    }
#pragma unroll
    for (int kf = 0; kf < 4; kf++)
#pragma unroll
        for (int i = 0; i < 6; i++)
            acc[i] = __builtin_amdgcn_mfma_f32_16x16x32_bf16(haf[kf], whh[i][kf], acc[i], 0, 0, 0);

    float rstf[4] = {1.f, 1.f, 1.f, 1.f};
    if (t > 0) {
        int4 dd = *(const int4*)&doneL[(t - 1) * 16 + 4 * lg];
        rstf[0] = dd.x ? 0.f : 1.f; rstf[1] = dd.y ? 0.f : 1.f;
        rstf[2] = dd.z ? 0.f : 1.f; rstf[3] = dd.w ? 0.f : 1.f;
    }
#pragma unroll
    for (int cs = 0; cs < 2; cs++) {
#pragma unroll
        for (int r = 0; r < 4; r++) {
            float rg = __builtin_amdgcn_rcpf(1.f + __expf(-acc[cs][r]));
            float zg = __builtin_amdgcn_rcpf(1.f + __expf(-acc[2 + cs][r]));
            float xn = (r == 0) ? bflo(xn8[cs].x) : (r == 1) ? bfhi(xn8[cs].x)
                     : (r == 2) ? bflo(xn8[cs].y) : bfhi(xn8[cs].y);
            float aa = fmaf(rg, acc[4 + cs][r], xn);
            float ng = 1.f - 2.f * __builtin_amdgcn_rcpf(__expf(2.f * aa) + 1.f);
            float hp = h_reg[cs][r] * rstf[r];
            float hn = (1.f - zg) * ng + zg * hp;
            h_reg[cs][r] = hn;                       // un-reset
            hTn[(4 * lg + r) * 136 + 16 * j + 64 * cs + q] = f2bf(hn);
        }
    }
}

__device__ __forceinline__ void fc_epilogue(
    const short* hTp, const short8 (&wfc)[2][4], const float (&cbf)[2],
    float* __restrict__ out, int t_last, int bg, int j, int q, int lg) {
    short8 haf[4];
#pragma unroll
    for (int kf = 0; kf < 4; kf++)
        haf[kf] = *(const short8*)&hTp[q * 136 + kf * 32 + 8 * lg];
    f32x4 fca[2];
    { f32x4 a = {cbf[0], cbf[0], cbf[0], cbf[0]}; fca[0] = a; }
    { f32x4 a = {cbf[1], cbf[1], cbf[1], cbf[1]}; fca[1] = a; }
#pragma unroll
    for (int kf = 0; kf < 4; kf++)
#pragma unroll
        for (int cs = 0; cs < 2; cs++)
            fca[cs] = __builtin_amdgcn_mfma_f32_16x16x32_bf16(haf[kf], wfc[cs][kf], fca[cs], 0, 0, 0);
#pragma unroll
    for (int cs = 0; cs < 2; cs++)
#pragma unroll
        for (int r = 0; r < 4; r++) {
            int bb = 4 * lg + r, c = 16 * j + 64 * cs + q;
            float v = fca[cs][r];
            float e = __expf(v) - 1.f;
            v = v > 0.f ? v : e;
            out[(((size_t)(bg * 16 + bb)) * Tt + t_last) * Hd + c] = v;
        }
}

#define RAW_BARRIER() do { \
    __builtin_amdgcn_sched_barrier(0); \
    __builtin_amdgcn_s_waitcnt(0xC07F); \
    __builtin_amdgcn_s_barrier(); \
    __builtin_amdgcn_sched_barrier(0); } while (0)

// K3: dual-recurrence blocks. Block (bg, p) owns chunks ck=2p and 2p+1 of
// batch-group bg (CL=16). Two register contexts share weights/doneL; the
// joint loop runs stepA;stepB back-to-back in ONE basic block so the
// scheduler interleaves two independent chains (2x ILP), and the barrier
// is amortized over 2 steps. 512 blocks -> proven 2 blocks/CU residency.
__global__ __launch_bounds__(256)
void gru_dual(const short* __restrict__ xi_l, const int* __restrict__ done,
              const float* __restrict__ h0,
              const float* __restrict__ bhh, const float* __restrict__ fcb,
              const short* __restrict__ wHh, const short* __restrict__ wFc,
              float* __restrict__ out, float* __restrict__ hlast) {
    __shared__ short hTA[2][16 * 136], hTB[2][16 * 136];
    __shared__ int doneL[Tt * 16];
    __shared__ int rbLA[16], rbLB[16];
    const int tid = threadIdx.x, j = tid >> 6, ln = tid & 63;
    const int q = ln & 15, lg = ln >> 4;
    const int bg = blockIdx.x, p = blockIdx.y;
    const int t_cA = (2 * p) * CL, t_endA = t_cA + CL;
    const int t_cB = t_endA, t_endB = t_cB + CL;

    {   // stage done[b][0..t_endB) -> doneL[t][b]
        const int b = tid >> 4, i = tid & 15;
        const int* dp = done + (size_t)(bg * 16 + b) * Tt;
        for (int t = i; t < t_endB; t += 16) doneL[t * 16 + b] = dp[t];
    }
    __syncthreads();
    if (tid < 32) {   // last reset before t_cA (lanes 0-15) / t_cB (16-31)
        int b = tid & 15, start = (tid < 16 ? t_cA : t_cB) - 1;
        int r = 0;
        for (int t = start; t >= 0; --t)
            if (doneL[t * 16 + b]) { r = t + 1; break; }
        (tid < 16 ? rbLA : rbLB)[b] = r;
    }
    __syncthreads();
    int rminA = rbLA[0], rminB = rbLB[0];
#pragma unroll
    for (int b = 1; b < 16; b++) {
        rminA = min(rminA, rbLA[b]);
        rminB = min(rminB, rbLB[b]);
    }

    short8 whh[6][4], wfc[2][4];
#pragma unroll
    for (int i = 0; i < 6; i++)
#pragma unroll
        for (int kf = 0; kf < 4; kf++)
            whh[i][kf] = *(const short8*)&wHh[(((j + 4 * i) * 4 + kf) * 64 + ln) * 8];
#pragma unroll
    for (int cs = 0; cs < 2; cs++)
#pragma unroll
        for (int kf = 0; kf < 4; kf++)
            wfc[cs][kf] = *(const short8*)&wFc[(((j + 4 * cs) * 4 + kf) * 64 + ln) * 8];
    float cbn[2], cbf[2];
#pragma unroll
    for (int cs = 0; cs < 2; cs++) {
        int c = 16 * j + 64 * cs + q;
        cbn[cs] = bhh[256 + c];
        cbf[cs] = fcb[c];
    }

    float h_regA[2][4], h_regB[2][4];
#pragma unroll
    for (int cs = 0; cs < 2; cs++)
#pragma unroll
        for (int r = 0; r < 4; r++) {
            int bb = 4 * lg + r, c = 16 * j + 64 * cs + q;
            const float* hp = &h0[(size_t)(bg * 16 + bb) * Hd + c];
            h_regA[cs][r] = (rbLA[bb] == 0) ? *hp : 0.f;
            h_regB[cs][r] = (rbLB[bb] == 0) ? *hp : 0.f;
        }
    {   // init hT slots (h0 if rb==0 else 0)
        int row = tid >> 4, c0 = (tid & 15) * 8;
        short8 z8 = {0,0,0,0,0,0,0,0};
        short8 h08 = z8;
        if (rbLA[row] == 0 || rbLB[row] == 0) {
            const float* hp = &h0[(size_t)(bg * 16 + row) * Hd + c0];
            f32x4 u0 = *(const f32x4*)&hp[0], u1 = *(const f32x4*)&hp[4];
#pragma unroll
            for (int i = 0; i < 4; i++) { h08[i] = f2bf(u0[i]); h08[i+4] = f2bf(u1[i]); }
        }
        *(short8*)&hTA[rminA & 1][row * 136 + c0] = (rbLA[row] == 0) ? h08 : z8;
        *(short8*)&hTB[rminB & 1][row * 136 + c0] = (rbLB[row] == 0) ? h08 : z8;
    }
    __syncthreads();

    const uint2* xpA = (const uint2*)xi_l + ((size_t)bg * Tt + rminA) * 1536 + j * 64 + ln;
    const uint2* xpB = (const uint2*)xi_l + ((size_t)bg * Tt + rminB) * 1536 + j * 64 + ln;
    uint2 curA[6], curB[6];
#pragma unroll
    for (int i = 0; i < 6; i++) { curA[i] = xpA[i * 256]; curB[i] = xpB[i * 256]; }
    xpA += 1536; xpB += 1536;

    const int lenA = t_endA - rminA, lenB = t_endB - rminB;
    int tA = rminA, tB = rminB;
    const int extraA = max(0, lenA - lenB), extraB = max(0, lenB - lenA);
#pragma unroll 1
    for (int r = 0; r < extraA; ++r) {   // longer-A pre-phase
        gru_step(tA, t_cA, tA + 1 < t_endA, &hTA[tA & 1][0], &hTA[(tA + 1) & 1][0],
                 curA, xpA, h_regA, doneL, whh, wfc, cbn, cbf, out, bg, j, q, lg);
        xpA += 1536; ++tA;
        RAW_BARRIER();
    }
#pragma unroll 1
    for (int r = 0; r < extraB; ++r) {   // longer-B pre-phase
        gru_step(tB, t_cB, tB + 1 < t_endB, &hTB[tB & 1][0], &hTB[(tB + 1) & 1][0],
                 curB, xpB, h_regB, doneL, whh, wfc, cbn, cbf, out, bg, j, q, lg);
        xpB += 1536; ++tB;
        RAW_BARRIER();
    }
    const int joint = min(lenA, lenB);
#pragma unroll 1
    for (int r = 0; r < joint; ++r) {    // joint phase: A and B interleaved
        gru_step(tA, t_cA, tA + 1 < t_endA, &hTA[tA & 1][0], &hTA[(tA + 1) & 1][0],
                 curA, xpA, h_regA, doneL, whh, wfc, cbn, cbf, out, bg, j, q, lg);
        gru_step(tB, t_cB, tB + 1 < t_endB, &hTB[tB & 1][0], &hTB[(tB + 1) & 1][0],
                 curB, xpB, h_regB, doneL, whh, wfc, cbn, cbf, out, bg, j, q, lg);
        xpA += 1536; xpB += 1536; ++tA; ++tB;
        RAW_BARRIER();
    }

    fc_epilogue(&hTA[t_endA & 1][0], wfc, cbf, out, t_endA - 1, bg, j, q, lg);
    fc_epilogue(&hTB[t_endB & 1][0], wfc, cbf, out, t_endB - 1, bg, j, q, lg);
    if (p == NPAIR - 1) {   // h after step 255 (chunk 15 = B of last pair)
#pragma unroll
        for (int cs = 0; cs < 2; cs++)
#pragma unroll
            for (int r = 0; r < 4; r++) {
                int bb = 4 * lg + r, c = 16 * j + 64 * cs + q;
                hlast[(size_t)(bg * 16 + bb) * Hd + c] = h_regB[cs][r];
            }
    }
}

extern "C" void kernel_launch(void* const* d_in, const int* in_sizes, int n_in,
                              void* d_out, int out_size, void* d_ws, size_t ws_size,
                              hipStream_t stream) {
    const float* x   = (const float*)d_in[0];
    const float* h0  = (const float*)d_in[1];
    const int*   dn  = (const int*)d_in[2];
    const float* Wih = (const float*)d_in[3];
    const float* Whh = (const float*)d_in[4];
    const float* bih = (const float*)d_in[5];
    const float* bhh = (const float*)d_in[6];
    const float* fcW = (const float*)d_in[7];
    const float* fcb = (const float*)d_in[8];

    short* wIh = (short*)d_ws;                 // 96 KB
    short* wHh = wIh + 49152;                  // 96 KB
    short* wFc = wHh + 49152;                  // 32 KB
    short* xi_l = wFc + 16384;                 // full-T xi: 201 MB
    float* out = (float*)d_out;
    float* hlast = out + (size_t)Bb * Tt * Hd;

    prep_weights<<<56, 256, 0, stream>>>(Wih, Whh, fcW, wIh, wHh, wFc);
    xi_gemm<<<dim3(64, Tt / 8), 512, 0, stream>>>(x, bih, bhh, wIh, xi_l);
    gru_dual<<<dim3(64, NPAIR), 256, 0, stream>>>(xi_l, dn, h0, bhh, fcb,
                                                  wHh, wFc, out, hlast);
}

// Round 17
// 166.697 us; speedup vs baseline: 1.3428x; 1.2659x over previous
//
#include <hip/hip_runtime.h>
#include <hip/hip_bf16.h>
#include <math.h>

#define Hd 128
#define Tt 256
#define Bb 1024
#define CL 32           // time-chunk length
#define NCK (Tt / CL)   // 8 chunks

typedef __attribute__((ext_vector_type(8))) short short8;
typedef __attribute__((ext_vector_type(4))) float f32x4;

__device__ __forceinline__ short f2bf(float f) {
    unsigned u = __float_as_uint(f);
    u += 0x7fffu + ((u >> 16) & 1u);   // RNE
    return (short)(u >> 16);
}
__device__ __forceinline__ float bflo(unsigned u) { return __uint_as_float(u << 16); }
__device__ __forceinline__ float bfhi(unsigned u) { return __uint_as_float(u & 0xffff0000u); }

// Weights -> bf16 MFMA B-frag layout [nt][kf][lane][8].  (verbatim)
__global__ void prep_weights(const float* __restrict__ Wih,
                             const float* __restrict__ Whh,
                             const float* __restrict__ fcW,
                             short* __restrict__ oIh, short* __restrict__ oHh,
                             short* __restrict__ oFc) {
    int t = blockIdx.x * 256 + threadIdx.x;
    if (t >= 14336) return;
    const float* src;
    short* dst;
    if (t < 6144)       { src = Wih; dst = oIh + t * 8; }
    else if (t < 12288) { t -= 6144;  src = Whh; dst = oHh + t * 8; }
    else                { t -= 12288; src = fcW; dst = oFc + t * 8; }
    int lane = t & 63, kf = (t >> 6) & 3, nt = t >> 8;
    const float* s = src + (nt * 16 + (lane & 15)) * 128 + kf * 32 + 8 * (lane >> 4);
#pragma unroll
    for (int j = 0; j < 8; j++) dst[j] = f2bf(s[j]);
}

// K2: xi = x@W_ih^T (+bih, +bhh for r/z cols) in C-frag order.
// R14 version: 8 frames per block (2048 blocks) -- halves per-block W_ih
// L2 re-reads + fixed overheads; unroll 2 on mt for ILP. ~70 us measured.
__global__ __launch_bounds__(512)
void xi_gemm(const float* __restrict__ x, const float* __restrict__ bih,
             const float* __restrict__ bhh, const short* __restrict__ wIh,
             short* __restrict__ xi_l) {
    __shared__ short xs[128 * 136];
    const int tid = threadIdx.x, wv = tid >> 6, ln = tid & 63;
    const int q = ln & 15, lg = ln >> 4;
    const int bg = blockIdx.x;
    const int sl0 = blockIdx.y * 8;
    {
        const int row = tid >> 2, kq = tid & 3;
        const int b = row & 15, dt = row >> 4;
        const float* xp = x + (((size_t)(bg * 16 + b)) * Tt + (sl0 + dt)) * Hd + kq * 32;
        short* dp = &xs[row * 136 + kq * 32];
#pragma unroll
        for (int h = 0; h < 2; h++) {
            f32x4 u0 = *(const f32x4*)&xp[16 * h];
            f32x4 u1 = *(const f32x4*)&xp[16 * h + 4];
            f32x4 u2 = *(const f32x4*)&xp[16 * h + 8];
            f32x4 u3 = *(const f32x4*)&xp[16 * h + 12];
            short8 s0, s1;
#pragma unroll
            for (int i = 0; i < 4; i++) { s0[i] = f2bf(u0[i]); s0[i+4] = f2bf(u1[i]);
                                          s1[i] = f2bf(u2[i]); s1[i+4] = f2bf(u3[i]); }
            *(short8*)(dp + 16 * h) = s0;
            *(short8*)(dp + 16 * h + 8) = s1;
        }
    }
    __syncthreads();
    short8 wb[3][4];
#pragma unroll
    for (int i = 0; i < 3; i++)
#pragma unroll
        for (int kf = 0; kf < 4; kf++)
            wb[i][kf] = *(const short8*)&wIh[(((wv + 8 * i) * 4 + kf) * 64 + ln) * 8];
    float biasv[3];
#pragma unroll
    for (int i = 0; i < 3; i++) {
        int c = (wv + 8 * i) * 16 + q;
        biasv[i] = bih[c] + (c < 256 ? bhh[c] : 0.f);
    }
#pragma unroll 2
    for (int mt = 0; mt < 8; mt++) {
        short8 af[4];
#pragma unroll
        for (int kf = 0; kf < 4; kf++)
            af[kf] = *(const short8*)&xs[(mt * 16 + q) * 136 + kf * 32 + 8 * lg];
        f32x4 c0 = {0,0,0,0}, c1 = {0,0,0,0}, c2 = {0,0,0,0};
#pragma unroll
        for (int kf = 0; kf < 4; kf++) {
            c0 = __builtin_amdgcn_mfma_f32_16x16x32_bf16(af[kf], wb[0][kf], c0, 0, 0, 0);
            c1 = __builtin_amdgcn_mfma_f32_16x16x32_bf16(af[kf], wb[1][kf], c1, 0, 0, 0);
            c2 = __builtin_amdgcn_mfma_f32_16x16x32_bf16(af[kf], wb[2][kf], c2, 0, 0, 0);
        }
#pragma unroll
        for (int i = 0; i < 3; i++) {
            f32x4 cc = (i == 0) ? c0 : (i == 1) ? c1 : c2;
            unsigned d0 = (unsigned)(unsigned short)f2bf(cc[0] + biasv[i]) |
                          ((unsigned)(unsigned short)f2bf(cc[1] + biasv[i]) << 16);
            unsigned d1 = (unsigned)(unsigned short)f2bf(cc[2] + biasv[i]) |
                          ((unsigned)(unsigned short)f2bf(cc[3] + biasv[i]) << 16);
            uint2 dd = {d0, d1};
            ((uint2*)xi_l)[(((size_t)bg * Tt + (sl0 + mt)) * 24 + (wv + 8 * i)) * 64 + ln] = dd;
        }
    }
}

// K3: R12's gru_chunk VERBATIM (best measured: 92.8 us; 4 waves, CL=32,
// depth-1 prefetch, semantic lgkm-only barrier, setprio). R11/R14/R15/R16
// all proved: any added state/waves breaks the 2-blocks/CU residency.
__global__ __launch_bounds__(256)
void gru_chunk(const short* __restrict__ xi_l, const int* __restrict__ done,
               const float* __restrict__ h0,
               const float* __restrict__ bhh, const float* __restrict__ fcb,
               const short* __restrict__ wHh, const short* __restrict__ wFc,
               float* __restrict__ out, float* __restrict__ hlast) {
    __shared__ short hT[2][16 * 136];
    __shared__ int doneL[Tt * 16];
    __shared__ int rbL[16];
    const int tid = threadIdx.x, j = tid >> 6, ln = tid & 63;
    const int q = ln & 15, lg = ln >> 4;
    const int bg = blockIdx.x, ck = blockIdx.y;
    const int t_c = ck * CL, t_end = t_c + CL;

    {   // stage done[b][0..t_end) -> doneL[t][b]
        const int b = tid >> 4, i = tid & 15;
        const int* dp = done + (size_t)(bg * 16 + b) * Tt;
        for (int t = i; t < t_end; t += 16) doneL[t * 16 + b] = dp[t];
    }
    __syncthreads();
    if (tid < 16) {   // last reset before t_c
        int r = 0;
        for (int t = t_c - 1; t >= 0; --t)
            if (doneL[t * 16 + tid]) { r = t + 1; break; }
        rbL[tid] = r;
    }
    __syncthreads();
    int rmin = rbL[0];
#pragma unroll
    for (int b = 1; b < 16; b++) rmin = min(rmin, rbL[b]);

    short8 whh[6][4], wfc[2][4];
#pragma unroll
    for (int i = 0; i < 6; i++)
#pragma unroll
        for (int kf = 0; kf < 4; kf++)
            whh[i][kf] = *(const short8*)&wHh[(((j + 4 * i) * 4 + kf) * 64 + ln) * 8];
#pragma unroll
    for (int cs = 0; cs < 2; cs++)
#pragma unroll
        for (int kf = 0; kf < 4; kf++)
            wfc[cs][kf] = *(const short8*)&wFc[(((j + 4 * cs) * 4 + kf) * 64 + ln) * 8];
    float cbn[2], cbf[2];
#pragma unroll
    for (int cs = 0; cs < 2; cs++) {
        int c = 16 * j + 64 * cs + q;
        cbn[cs] = bhh[256 + c];
        cbf[cs] = fcb[c];
    }

    float h_reg[2][4];
#pragma unroll
    for (int cs = 0; cs < 2; cs++)
#pragma unroll
        for (int r = 0; r < 4; r++) {
            int bb = 4 * lg + r, c = 16 * j + 64 * cs + q;
            h_reg[cs][r] = (rbL[bb] == 0) ? h0[(size_t)(bg * 16 + bb) * Hd + c] : 0.f;
        }
    {   // hT[rmin&1] <- h_init (h0 if r_b==0 else 0)
        int row = tid >> 4, c0 = (tid & 15) * 8;
        short8 s0 = {0,0,0,0,0,0,0,0};
        if (rbL[row] == 0) {
            const float* hp = &h0[(size_t)(bg * 16 + row) * Hd + c0];
            f32x4 u0 = *(const f32x4*)&hp[0], u1 = *(const f32x4*)&hp[4];
#pragma unroll
            for (int i = 0; i < 4; i++) { s0[i] = f2bf(u0[i]); s0[i+4] = f2bf(u1[i]); }
        }
        *(short8*)&hT[rmin & 1][row * 136 + c0] = s0;
    }
    __syncthreads();

    // xi pointer: tile (j+4i) at xp + i*256 (uint2), one t = +1536
    const uint2* xp = (const uint2*)xi_l + ((size_t)bg * Tt + rmin) * 1536 + j * 64 + ln;
    uint2 cur[6];
#pragma unroll
    for (int i = 0; i < 6; i++) cur[i] = xp[i * 256];
    xp += 1536;

#pragma unroll 1
    for (int t = rmin; t < t_end; ++t) {
        const short* hTp = &hT[t & 1][0];
        short* hTn = &hT[(t + 1) & 1][0];
        short8 haf[4];
#pragma unroll
        for (int kf = 0; kf < 4; kf++)
            haf[kf] = *(const short8*)&hTp[q * 136 + kf * 32 + 8 * lg];

        // consume cur(t) -> acc init + xn8, then ISSUE loads for t+1 (older
        // than this iter's stores in vmcnt order)
        f32x4 acc[6];
#pragma unroll
        for (int i = 0; i < 4; i++) {
            f32x4 a = {bflo(cur[i].x), bfhi(cur[i].x), bflo(cur[i].y), bfhi(cur[i].y)};
            acc[i] = a;
        }
        { f32x4 a = {cbn[0], cbn[0], cbn[0], cbn[0]}; acc[4] = a; }
        { f32x4 a = {cbn[1], cbn[1], cbn[1], cbn[1]}; acc[5] = a; }
        uint2 xn8[2] = {cur[4], cur[5]};
        if (t + 1 < t_end) {
#pragma unroll
            for (int i = 0; i < 6; i++) cur[i] = xp[i * 256];
        }
        xp += 1536;

        if (t > t_c) {   // FC+ELU+stores for frame t-1 (un-reset haf)
            f32x4 fca[2];
            { f32x4 a = {cbf[0], cbf[0], cbf[0], cbf[0]}; fca[0] = a; }
            { f32x4 a = {cbf[1], cbf[1], cbf[1], cbf[1]}; fca[1] = a; }
#pragma unroll
            for (int kf = 0; kf < 4; kf++)
#pragma unroll
                for (int cs = 0; cs < 2; cs++)
                    fca[cs] = __builtin_amdgcn_mfma_f32_16x16x32_bf16(haf[kf], wfc[cs][kf], fca[cs], 0, 0, 0);
#pragma unroll
            for (int cs = 0; cs < 2; cs++)
#pragma unroll
                for (int r = 0; r < 4; r++) {
                    int bb = 4 * lg + r, c = 16 * j + 64 * cs + q;
                    float v = fca[cs][r];
                    float e = __expf(v) - 1.f;
                    v = v > 0.f ? v : e;
                    out[(((size_t)(bg * 16 + bb)) * Tt + (t - 1)) * Hd + c] = v;
                }
        }

        if (t > 0) {   // reset haf in place (FC above used un-reset value)
            int dn = doneL[(t - 1) * 16 + q];
            short8 z8 = {0,0,0,0,0,0,0,0};
#pragma unroll
            for (int kf = 0; kf < 4; kf++) haf[kf] = dn ? z8 : haf[kf];
        }
        __builtin_amdgcn_s_setprio(1);   // favor the h-critical region
#pragma unroll
        for (int kf = 0; kf < 4; kf++)
#pragma unroll
            for (int i = 0; i < 6; i++)
                acc[i] = __builtin_amdgcn_mfma_f32_16x16x32_bf16(haf[kf], whh[i][kf], acc[i], 0, 0, 0);

        float rstf[4] = {1.f, 1.f, 1.f, 1.f};
        if (t > 0) {
            int4 dd = *(const int4*)&doneL[(t - 1) * 16 + 4 * lg];
            rstf[0] = dd.x ? 0.f : 1.f; rstf[1] = dd.y ? 0.f : 1.f;
            rstf[2] = dd.z ? 0.f : 1.f; rstf[3] = dd.w ? 0.f : 1.f;
        }
#pragma unroll
        for (int cs = 0; cs < 2; cs++) {
#pragma unroll
            for (int r = 0; r < 4; r++) {
                float rg = __builtin_amdgcn_rcpf(1.f + __expf(-acc[cs][r]));
                float zg = __builtin_amdgcn_rcpf(1.f + __expf(-acc[2 + cs][r]));
                float xn = (r == 0) ? bflo(xn8[cs].x) : (r == 1) ? bfhi(xn8[cs].x)
                         : (r == 2) ? bflo(xn8[cs].y) : bfhi(xn8[cs].y);
                float aa = fmaf(rg, acc[4 + cs][r], xn);
                float ng = 1.f - 2.f * __builtin_amdgcn_rcpf(__expf(2.f * aa) + 1.f);
                float hp = h_reg[cs][r] * rstf[r];
                float hn = (1.f - zg) * ng + zg * hp;
                h_reg[cs][r] = hn;                       // un-reset
                hTn[(4 * lg + r) * 136 + 16 * j + 64 * cs + q] = f2bf(hn);
            }
        }
        __builtin_amdgcn_s_setprio(0);
        // raw barrier: lgkmcnt(0) only, semantic intrinsic
        __builtin_amdgcn_sched_barrier(0);
        __builtin_amdgcn_s_waitcnt(0xC07F);
        __builtin_amdgcn_s_barrier();
        __builtin_amdgcn_sched_barrier(0);
    }
    {   // epilogue FC for frame t_end-1 (slot t_end&1 holds h_{t_end-1})
        const short* hTp = &hT[t_end & 1][0];
        short8 haf[4];
#pragma unroll
        for (int kf = 0; kf < 4; kf++)
            haf[kf] = *(const short8*)&hTp[q * 136 + kf * 32 + 8 * lg];
        f32x4 fca[2];
        { f32x4 a = {cbf[0], cbf[0], cbf[0], cbf[0]}; fca[0] = a; }
        { f32x4 a = {cbf[1], cbf[1], cbf[1], cbf[1]}; fca[1] = a; }
#pragma unroll
        for (int kf = 0; kf < 4; kf++)
#pragma unroll
            for (int cs = 0; cs < 2; cs++)
                fca[cs] = __builtin_amdgcn_mfma_f32_16x16x32_bf16(haf[kf], wfc[cs][kf], fca[cs], 0, 0, 0);
#pragma unroll
        for (int cs = 0; cs < 2; cs++)
#pragma unroll
            for (int r = 0; r < 4; r++) {
                int bb = 4 * lg + r, c = 16 * j + 64 * cs + q;
                float v = fca[cs][r];
                float e = __expf(v) - 1.f;
                v = v > 0.f ? v : e;
                out[(((size_t)(bg * 16 + bb)) * Tt + (t_end - 1)) * Hd + c] = v;
            }
    }
    if (ck == NCK - 1) {   // h after step 255, un-reset
#pragma unroll
        for (int cs = 0; cs < 2; cs++)
#pragma unroll
            for (int r = 0; r < 4; r++) {
                int bb = 4 * lg + r, c = 16 * j + 64 * cs + q;
                hlast[(size_t)(bg * 16 + bb) * Hd + c] = h_reg[cs][r];
            }
    }
}

extern "C" void kernel_launch(void* const* d_in, const int* in_sizes, int n_in,
                              void* d_out, int out_size, void* d_ws, size_t ws_size,
                              hipStream_t stream) {
    const float* x   = (const float*)d_in[0];
    const float* h0  = (const float*)d_in[1];
    const int*   dn  = (const int*)d_in[2];
    const float* Wih = (const float*)d_in[3];
    const float* Whh = (const float*)d_in[4];
    const float* bih = (const float*)d_in[5];
    const float* bhh = (const float*)d_in[6];
    const float* fcW = (const float*)d_in[7];
    const float* fcb = (const float*)d_in[8];

    short* wIh = (short*)d_ws;                 // 96 KB
    short* wHh = wIh + 49152;                  // 96 KB
    short* wFc = wHh + 49152;                  // 32 KB
    short* xi_l = wFc + 16384;                 // full-T xi: 201 MB
    float* out = (float*)d_out;
    float* hlast = out + (size_t)Bb * Tt * Hd;

    prep_weights<<<56, 256, 0, stream>>>(Wih, Whh, fcW, wIh, wHh, wFc);
    xi_gemm<<<dim3(64, Tt / 8), 512, 0, stream>>>(x, bih, bhh, wIh, xi_l);
    gru_chunk<<<dim3(64, NCK), 256, 0, stream>>>(xi_l, dn, h0, bhh, fcb,
                                                 wHh, wFc, out, hlast);
}